// Round 17
// baseline (1576.545 us; speedup 1.0000x reference)
//
#include <hip/hip_runtime.h>
#include <math.h>

#define SL 1024
#define NW 256

typedef _Float16 half8 __attribute__((ext_vector_type(8)));
typedef _Float16 half2t __attribute__((ext_vector_type(2)));
typedef float f32x4 __attribute__((ext_vector_type(4)));

__device__ __forceinline__ float rcp_f(float v) { return __builtin_amdgcn_rcpf(v); }

// mfma_f32_16x16x32_f16 (layouts verified r2-r16, builtins only):
//   A: lane row m = lane&15, k = (lane>>4)*8+e;  B: lane col n = lane&15, same k
//   D: lane col n = lane&15, row m = (lane>>4)*4 + reg
// Broadcast-A (lane reads h row lane&1): acc regs 0,1 = batch rows 0,1.
// 8 waves, 2/SIMD, 256-reg cap, no spill (r15/r16 verified).
// r17: PHASE SWAP. Phase 1 = r+n tiles (f0,f1,f4,f5) -> rr-sigmoid, un and
// the LONG tanh chain all hide under phase 2 = z tiles (f2,f3). Post-MFMA
// tail is now just the z-sigmoid + 1 fma (~45 cyc vs r16's ~85). Butterfly
// moved into the phase-1 gate window. Per-acc kt order unchanged ->
// bitwise-same h trajectory as r15/r16.
__global__ __launch_bounds__(512, 2) void gru_mfma_kernel(
    const float* __restrict__ x, const float* __restrict__ w_ih,
    const float* __restrict__ w_hh, const float* __restrict__ b_ih,
    const float* __restrict__ b_hh, const float* __restrict__ fc_w,
    const float* __restrict__ fc_b, float* __restrict__ out)
{
    const int tid  = threadIdx.x;
    const int w    = tid >> 6;     // wave 0..7
    const int lane = tid & 63;
    const int c    = lane & 15;
    const int g    = lane >> 4;    // k-group for fragments
    const int gl   = g & 1;        // unit sub-tile parity for gate eval
    const int row  = g >> 1;       // this lane's batch row for gate eval
    const int row0 = blockIdx.x * 2;

    __shared__ float    x_lds[2][1026];                   // m values; idx0 = 0.5 (t=-1)
    __shared__ __align__(16) _Float16 h_lds[2][2][288];   // dbuf, 2 batch rows
    __shared__ float    dpart[SL][8][2];                  // per-step per-wave head partials
    __shared__ float    wsum[8][2];

    for (int i = tid; i < 2 * SL; i += 512) {
        int b = i >> 10, j = i & (SL - 1);
        x_lds[b][1 + j] = (x[(size_t)(row0 + b) * SL + j] + 1.0f) * 0.5f;
    }
    if (tid < 2) x_lds[tid][0] = 0.5f;
    for (int i = tid; i < 2 * 2 * 288; i += 512)
        ((_Float16*)h_lds)[i] = (_Float16)0.0f;

    // persistent B fragments: f = q*2 + jt -> w_hh row q*256 + (2w+jt)*16 + c
    half8 Bf[6][8];
    #pragma unroll
    for (int f = 0; f < 6; ++f) {
        const int q = f >> 1, jt = f & 1;
        const int urow = q * NW + (2 * w + jt) * 16 + c;
        #pragma unroll
        for (int kt = 0; kt < 8; ++kt) {
            const float* p = w_hh + (size_t)urow * NW + kt * 32 + g * 8;
            float4 lo = *(const float4*)p;
            float4 hi = *(const float4*)(p + 4);
            half8 hb;
            hb[0] = (_Float16)lo.x; hb[1] = (_Float16)lo.y;
            hb[2] = (_Float16)lo.z; hb[3] = (_Float16)lo.w;
            hb[4] = (_Float16)hi.x; hb[5] = (_Float16)hi.y;
            hb[6] = (_Float16)hi.z; hb[7] = (_Float16)hi.w;
            Bf[f][kt] = hb;
        }
    }

    // gate constants for THIS lane's unit u = 32w + 16gl + c (f16-packed)
    const int u = 32 * w + 16 * gl + c;
    half2t pkr, pkz, pkn, pkh;   // pkh = (bhn, wd)
    {
        float w0, w1;
        w0 = w_ih[2 * u]; w1 = w_ih[2 * u + 1];
        pkr[0] = (_Float16)(w1 + b_ih[u] + b_hh[u]);
        pkr[1] = (_Float16)(w0 - w1);
        w0 = w_ih[2 * (NW + u)]; w1 = w_ih[2 * (NW + u) + 1];
        pkz[0] = (_Float16)(w1 + b_ih[NW + u] + b_hh[NW + u]);
        pkz[1] = (_Float16)(w0 - w1);
        w0 = w_ih[2 * (2 * NW + u)]; w1 = w_ih[2 * (2 * NW + u) + 1];
        pkn[0] = (_Float16)(w1 + b_ih[2 * NW + u]);
        pkn[1] = (_Float16)(w0 - w1);
        pkh[0] = (_Float16)b_hh[2 * NW + u];
        pkh[1] = (_Float16)(fc_w[u] - fc_w[NW + u]);
    }

    const f32x4 zc = {0.f, 0.f, 0.f, 0.f};   // loop-invariant SrcC zero
    float h0 = 0.f;                           // this lane's h[u] for its row
    float p_prev = 0.f;                       // deferred head partial (t-1)

    __syncthreads();

    #pragma unroll 1
    for (int t = 0; t < SL; ++t) {
        const int cur = t & 1, nxt = cur ^ 1;

        const _Float16* hb = &h_lds[cur][lane & 1][g * 8];
        const float m = x_lds[row][t];

        // ---- phase 1: r tiles (f0,f1) + n tiles (f4,f5), all kt ----
        f32x4 accA[4];
        {
            half8 A = *(const half8*)(hb);
            accA[0] = __builtin_amdgcn_mfma_f32_16x16x32_f16(A, Bf[0][0], zc, 0, 0, 0);
            accA[1] = __builtin_amdgcn_mfma_f32_16x16x32_f16(A, Bf[1][0], zc, 0, 0, 0);
            accA[2] = __builtin_amdgcn_mfma_f32_16x16x32_f16(A, Bf[4][0], zc, 0, 0, 0);
            accA[3] = __builtin_amdgcn_mfma_f32_16x16x32_f16(A, Bf[5][0], zc, 0, 0, 0);
        }
        #pragma unroll
        for (int kt = 1; kt < 8; ++kt) {
            half8 A = *(const half8*)(hb + kt * 32);
            accA[0] = __builtin_amdgcn_mfma_f32_16x16x32_f16(A, Bf[0][kt], accA[0], 0, 0, 0);
            accA[1] = __builtin_amdgcn_mfma_f32_16x16x32_f16(A, Bf[1][kt], accA[1], 0, 0, 0);
            accA[2] = __builtin_amdgcn_mfma_f32_16x16x32_f16(A, Bf[4][kt], accA[2], 0, 0, 0);
            accA[3] = __builtin_amdgcn_mfma_f32_16x16x32_f16(A, Bf[5][kt], accA[3], 0, 0, 0);
        }

        // r-sigmoid + n-tanh chains + deferred butterfly -- all independent of
        // phase 2; scheduler interleaves them under the z-tile MFMAs
        const float ar = row ? (gl ? accA[1][1] : accA[0][1]) : (gl ? accA[1][0] : accA[0][0]);
        const float an = row ? (gl ? accA[3][1] : accA[2][1]) : (gl ? accA[3][0] : accA[2][0]);
        const float vr = ar + fmaf(m, (float)pkr[1], (float)pkr[0]);
        const float rr = rcp_f(1.f + __expf(-vr));
        const float un = fmaf(rr, an + (float)pkh[0], fmaf(m, (float)pkn[1], (float)pkn[0]));
        const float ng = fmaf(-2.f, rcp_f(1.f + __expf(2.f * un)), 1.f);

        {
            float p = p_prev;
            p += __shfl_xor(p, 1);  p += __shfl_xor(p, 2);
            p += __shfl_xor(p, 4);  p += __shfl_xor(p, 8);
            p += __shfl_xor(p, 16);
            if (t != 0 && (lane & 31) == 0) dpart[t - 1][w][row] = p;
        }

        // ---- phase 2: z tiles (f2,f3), all kt ----
        f32x4 accB[2];
        {
            half8 A = *(const half8*)(hb);
            accB[0] = __builtin_amdgcn_mfma_f32_16x16x32_f16(A, Bf[2][0], zc, 0, 0, 0);
            accB[1] = __builtin_amdgcn_mfma_f32_16x16x32_f16(A, Bf[3][0], zc, 0, 0, 0);
        }
        #pragma unroll
        for (int kt = 1; kt < 8; ++kt) {
            half8 A = *(const half8*)(hb + kt * 32);
            accB[0] = __builtin_amdgcn_mfma_f32_16x16x32_f16(A, Bf[2][kt], accB[0], 0, 0, 0);
            accB[1] = __builtin_amdgcn_mfma_f32_16x16x32_f16(A, Bf[3][kt], accB[1], 0, 0, 0);
        }

        // short z tail: sigmoid + 1 fma
        const float az = row ? (gl ? accB[1][1] : accB[0][1]) : (gl ? accB[1][0] : accB[0][0]);
        const float vz = az + fmaf(m, (float)pkz[1], (float)pkz[0]);
        const float zz = rcp_f(1.f + __expf(-vz));
        const float hn = fmaf(zz, h0 - ng, ng);
        h0 = hn;

        // own h-store (64 lanes cover units 32w..32w+31 x rows 0,1)
        h_lds[nxt][row][u] = (_Float16)hn;

        // head partial for THIS step, reduced at the top of the next iteration
        p_prev = hn * (float)pkh[1];

        __syncthreads();
    }

    // final head butterfly (t = SL-1)
    {
        float p = p_prev;
        p += __shfl_xor(p, 1);  p += __shfl_xor(p, 2);
        p += __shfl_xor(p, 4);  p += __shfl_xor(p, 8);
        p += __shfl_xor(p, 16);
        if ((lane & 31) == 0) dpart[SL - 1][w][row] = p;
    }
    __syncthreads();

    // post-loop: softplus over all steps, block reduction
    const float bd = fc_b[0] - fc_b[1];
    float lpp0 = 0.f, lpp1 = 0.f;
    #pragma unroll 1
    for (int t = tid; t < SL; t += 512) {
        float d0 = bd, d1 = bd;
        #pragma unroll
        for (int q = 0; q < 8; ++q) { d0 += dpart[t][q][0]; d1 += dpart[t][q][1]; }
        const float u0 = (x_lds[0][t + 1] > 0.5f) ? -d0 : d0;
        const float u1 = (x_lds[1][t + 1] > 0.5f) ? -d1 : d1;
        lpp0 -= fmaxf(u0, 0.f) + __logf(1.f + __expf(-fabsf(u0)));
        lpp1 -= fmaxf(u1, 0.f) + __logf(1.f + __expf(-fabsf(u1)));
    }
    #pragma unroll
    for (int s = 1; s < 64; s <<= 1) {
        lpp0 += __shfl_xor(lpp0, s);
        lpp1 += __shfl_xor(lpp1, s);
    }
    if (lane == 0) { wsum[w][0] = lpp0; wsum[w][1] = lpp1; }
    __syncthreads();
    if (tid < 2) {
        float s = 0.f;
        #pragma unroll
        for (int q = 0; q < 8; ++q) s += wsum[q][tid];
        out[row0 + tid] = s;
    }
}

extern "C" void kernel_launch(void* const* d_in, const int* in_sizes, int n_in,
                              void* d_out, int out_size, void* d_ws, size_t ws_size,
                              hipStream_t stream) {
    const float* x    = (const float*)d_in[0];
    const float* w_ih = (const float*)d_in[1];
    const float* w_hh = (const float*)d_in[2];
    const float* b_ih = (const float*)d_in[3];
    const float* b_hh = (const float*)d_in[4];
    const float* fc_w = (const float*)d_in[5];
    const float* fc_b = (const float*)d_in[6];
    gru_mfma_kernel<<<256, 512, 0, stream>>>(
        x, w_ih, w_hh, b_ih, b_hh, fc_w, fc_b, (float*)d_out);
}

// Round 18
// 1041.716 us; speedup vs baseline: 1.5134x; 1.5134x over previous
//
#include <hip/hip_runtime.h>
#include <math.h>

#define SL 1024
#define NW 256

typedef _Float16 half8 __attribute__((ext_vector_type(8)));
typedef _Float16 half2t __attribute__((ext_vector_type(2)));
typedef float f32x4 __attribute__((ext_vector_type(4)));

__device__ __forceinline__ float rcp_f(float v) { return __builtin_amdgcn_rcpf(v); }

// mfma_f32_16x16x32_f16 (layouts verified r2-r16, builtins only):
//   A: lane row m = lane&15, k = (lane>>4)*8+e;  B: lane col n = lane&15, same k
//   D: lane col n = lane&15, row m = (lane>>4)*4 + reg
// Broadcast-A (lane reads h row lane&1): acc regs 0,1 = batch rows 0,1.
// 8 waves, 2/SIMD, 256-reg cap (no spill).
// r18 = r16 verbatim (best: 1043us). f-PHASED MFMA: phase 1 = r+z tiles
// (f0..f3) -> their two SHORT INDEPENDENT sigmoid chains hide under phase 2
// = n tiles (f4,f5). Butterfly at TOP of iteration (convergent shfls overlap
// the ds_read window; r17 proved mid-iteration placement stalls both pipes).
__global__ __launch_bounds__(512, 2) void gru_mfma_kernel(
    const float* __restrict__ x, const float* __restrict__ w_ih,
    const float* __restrict__ w_hh, const float* __restrict__ b_ih,
    const float* __restrict__ b_hh, const float* __restrict__ fc_w,
    const float* __restrict__ fc_b, float* __restrict__ out)
{
    const int tid  = threadIdx.x;
    const int w    = tid >> 6;     // wave 0..7
    const int lane = tid & 63;
    const int c    = lane & 15;
    const int g    = lane >> 4;    // k-group for fragments
    const int gl   = g & 1;        // unit sub-tile parity for gate eval
    const int row  = g >> 1;       // this lane's batch row for gate eval
    const int row0 = blockIdx.x * 2;

    __shared__ float    x_lds[2][1026];                   // m values; idx0 = 0.5 (t=-1)
    __shared__ __align__(16) _Float16 h_lds[2][2][288];   // dbuf, 2 batch rows
    __shared__ float    dpart[SL][8][2];                  // per-step per-wave head partials
    __shared__ float    wsum[8][2];

    for (int i = tid; i < 2 * SL; i += 512) {
        int b = i >> 10, j = i & (SL - 1);
        x_lds[b][1 + j] = (x[(size_t)(row0 + b) * SL + j] + 1.0f) * 0.5f;
    }
    if (tid < 2) x_lds[tid][0] = 0.5f;
    for (int i = tid; i < 2 * 2 * 288; i += 512)
        ((_Float16*)h_lds)[i] = (_Float16)0.0f;

    // persistent B fragments: f = q*2 + jt -> w_hh row q*256 + (2w+jt)*16 + c
    half8 Bf[6][8];
    #pragma unroll
    for (int f = 0; f < 6; ++f) {
        const int q = f >> 1, jt = f & 1;
        const int urow = q * NW + (2 * w + jt) * 16 + c;
        #pragma unroll
        for (int kt = 0; kt < 8; ++kt) {
            const float* p = w_hh + (size_t)urow * NW + kt * 32 + g * 8;
            float4 lo = *(const float4*)p;
            float4 hi = *(const float4*)(p + 4);
            half8 hb;
            hb[0] = (_Float16)lo.x; hb[1] = (_Float16)lo.y;
            hb[2] = (_Float16)lo.z; hb[3] = (_Float16)lo.w;
            hb[4] = (_Float16)hi.x; hb[5] = (_Float16)hi.y;
            hb[6] = (_Float16)hi.z; hb[7] = (_Float16)hi.w;
            Bf[f][kt] = hb;
        }
    }

    // gate constants for THIS lane's unit u = 32w + 16gl + c (f16-packed)
    const int u = 32 * w + 16 * gl + c;
    half2t pkr, pkz, pkn, pkh;   // pkh = (bhn, wd)
    {
        float w0, w1;
        w0 = w_ih[2 * u]; w1 = w_ih[2 * u + 1];
        pkr[0] = (_Float16)(w1 + b_ih[u] + b_hh[u]);
        pkr[1] = (_Float16)(w0 - w1);
        w0 = w_ih[2 * (NW + u)]; w1 = w_ih[2 * (NW + u) + 1];
        pkz[0] = (_Float16)(w1 + b_ih[NW + u] + b_hh[NW + u]);
        pkz[1] = (_Float16)(w0 - w1);
        w0 = w_ih[2 * (2 * NW + u)]; w1 = w_ih[2 * (2 * NW + u) + 1];
        pkn[0] = (_Float16)(w1 + b_ih[2 * NW + u]);
        pkn[1] = (_Float16)(w0 - w1);
        pkh[0] = (_Float16)b_hh[2 * NW + u];
        pkh[1] = (_Float16)(fc_w[u] - fc_w[NW + u]);
    }

    const f32x4 zc = {0.f, 0.f, 0.f, 0.f};   // loop-invariant SrcC zero
    float h0 = 0.f;                           // this lane's h[u] for its row
    float p_prev = 0.f;                       // deferred head partial (t-1)

    __syncthreads();

    #pragma unroll 1
    for (int t = 0; t < SL; ++t) {
        const int cur = t & 1, nxt = cur ^ 1;

        // deferred head butterfly for step t-1 (DS-pipe chain; overlaps MFMA)
        {
            float p = p_prev;
            p += __shfl_xor(p, 1);  p += __shfl_xor(p, 2);
            p += __shfl_xor(p, 4);  p += __shfl_xor(p, 8);
            p += __shfl_xor(p, 16);
            if (t != 0 && (lane & 31) == 0) dpart[t - 1][w][row] = p;
        }

        const _Float16* hb = &h_lds[cur][lane & 1][g * 8];
        const float m = x_lds[row][t];

        // ---- phase 1: r+z tiles (f0..f3), all kt ----
        f32x4 accA[4];
        {
            half8 A = *(const half8*)(hb);
            #pragma unroll
            for (int f = 0; f < 4; ++f)
                accA[f] = __builtin_amdgcn_mfma_f32_16x16x32_f16(A, Bf[f][0], zc, 0, 0, 0);
        }
        #pragma unroll
        for (int kt = 1; kt < 8; ++kt) {
            half8 A = *(const half8*)(hb + kt * 32);
            #pragma unroll
            for (int f = 0; f < 4; ++f)
                accA[f] = __builtin_amdgcn_mfma_f32_16x16x32_f16(A, Bf[f][kt], accA[f], 0, 0, 0);
        }

        // r/z gate chains -- independent of phase 2; scheduler interleaves
        const float ar = row ? (gl ? accA[1][1] : accA[0][1]) : (gl ? accA[1][0] : accA[0][0]);
        const float az = row ? (gl ? accA[3][1] : accA[2][1]) : (gl ? accA[3][0] : accA[2][0]);
        const float vr = ar + fmaf(m, (float)pkr[1], (float)pkr[0]);
        const float rr = rcp_f(1.f + __expf(-vr));
        const float vz = az + fmaf(m, (float)pkz[1], (float)pkz[0]);
        const float zz = rcp_f(1.f + __expf(-vz));

        // ---- phase 2: n tiles (f4..f5), all kt ----
        f32x4 accB[2];
        {
            half8 A = *(const half8*)(hb);
            accB[0] = __builtin_amdgcn_mfma_f32_16x16x32_f16(A, Bf[4][0], zc, 0, 0, 0);
            accB[1] = __builtin_amdgcn_mfma_f32_16x16x32_f16(A, Bf[5][0], zc, 0, 0, 0);
        }
        #pragma unroll
        for (int kt = 1; kt < 8; ++kt) {
            half8 A = *(const half8*)(hb + kt * 32);
            accB[0] = __builtin_amdgcn_mfma_f32_16x16x32_f16(A, Bf[4][kt], accB[0], 0, 0, 0);
            accB[1] = __builtin_amdgcn_mfma_f32_16x16x32_f16(A, Bf[5][kt], accB[1], 0, 0, 0);
        }

        // n-gate tail
        const float an = row ? (gl ? accB[1][1] : accB[0][1]) : (gl ? accB[1][0] : accB[0][0]);
        const float un = fmaf(rr, an + (float)pkh[0], fmaf(m, (float)pkn[1], (float)pkn[0]));
        const float ng = fmaf(-2.f, rcp_f(1.f + __expf(2.f * un)), 1.f);
        const float hn = fmaf(zz, h0 - ng, ng);
        h0 = hn;

        // own h-store (64 lanes cover units 32w..32w+31 x rows 0,1)
        h_lds[nxt][row][u] = (_Float16)hn;

        // head partial for THIS step, reduced at the top of the next iteration
        p_prev = hn * (float)pkh[1];

        __syncthreads();
    }

    // final head butterfly (t = SL-1)
    {
        float p = p_prev;
        p += __shfl_xor(p, 1);  p += __shfl_xor(p, 2);
        p += __shfl_xor(p, 4);  p += __shfl_xor(p, 8);
        p += __shfl_xor(p, 16);
        if ((lane & 31) == 0) dpart[SL - 1][w][row] = p;
    }
    __syncthreads();

    // post-loop: softplus over all steps, block reduction
    const float bd = fc_b[0] - fc_b[1];
    float lpp0 = 0.f, lpp1 = 0.f;
    #pragma unroll 1
    for (int t = tid; t < SL; t += 512) {
        float d0 = bd, d1 = bd;
        #pragma unroll
        for (int q = 0; q < 8; ++q) { d0 += dpart[t][q][0]; d1 += dpart[t][q][1]; }
        const float u0 = (x_lds[0][t + 1] > 0.5f) ? -d0 : d0;
        const float u1 = (x_lds[1][t + 1] > 0.5f) ? -d1 : d1;
        lpp0 -= fmaxf(u0, 0.f) + __logf(1.f + __expf(-fabsf(u0)));
        lpp1 -= fmaxf(u1, 0.f) + __logf(1.f + __expf(-fabsf(u1)));
    }
    #pragma unroll
    for (int s = 1; s < 64; s <<= 1) {
        lpp0 += __shfl_xor(lpp0, s);
        lpp1 += __shfl_xor(lpp1, s);
    }
    if (lane == 0) { wsum[w][0] = lpp0; wsum[w][1] = lpp1; }
    __syncthreads();
    if (tid < 2) {
        float s = 0.f;
        #pragma unroll
        for (int q = 0; q < 8; ++q) s += wsum[q][tid];
        out[row0 + tid] = s;
    }
}

extern "C" void kernel_launch(void* const* d_in, const int* in_sizes, int n_in,
                              void* d_out, int out_size, void* d_ws, size_t ws_size,
                              hipStream_t stream) {
    const float* x    = (const float*)d_in[0];
    const float* w_ih = (const float*)d_in[1];
    const float* w_hh = (const float*)d_in[2];
    const float* b_ih = (const float*)d_in[3];
    const float* b_hh = (const float*)d_in[4];
    const float* fc_w = (const float*)d_in[5];
    const float* fc_b = (const float*)d_in[6];
    gru_mfma_kernel<<<256, 512, 0, stream>>>(
        x, w_ih, w_hh, b_ih, b_hh, fc_w, fc_b, (float*)d_out);
}